// Round 8
// baseline (426.999 us; speedup 1.0000x reference)
//
#include <hip/hip_runtime.h>
#include <hip/hip_bf16.h>
#include <math.h>

#define N_ITEMS 100001
#define DIM 128
#define NP 3
#define SEQ 100
#define NB 256
#define G3 384           // 3*DIM
#define TAU 0.1f
#define EPS_C 0.01f

// ---------------- ws layout (float offsets) ----------------
#define OFF_G     0
#define OFF_C     300016
#define OFF_WXT   600032
#define OFF_WHT   747488
#define OFF_HLAST 894944
#define OFF_GX    993248
#define WS_FLOATS_PATHA (993248 + 29491200)

typedef float f32x4 __attribute__((ext_vector_type(4)));
typedef short s16x8 __attribute__((ext_vector_type(8)));
typedef unsigned int u32x4 __attribute__((ext_vector_type(4)));
typedef _Float16 f16x8 __attribute__((ext_vector_type(8)));
typedef __fp16 hf16x2 __attribute__((ext_vector_type(2)));   // cvt_pkrtz result type

__device__ __forceinline__ float sigmoidf_fast(float x) {
    return __builtin_amdgcn_rcpf(1.f + __builtin_amdgcn_exp2f(-1.4426950408889634f * x));
}
__device__ __forceinline__ float tanhf_fast(float x) {
    return 1.f - 2.f * __builtin_amdgcn_rcpf(1.f + __builtin_amdgcn_exp2f(2.8853900817779268f * x));
}
__device__ __forceinline__ unsigned short f2bf(float x) {
    union { float f; unsigned u; } v; v.f = x;
    unsigned r = v.u + 0x7fffu + ((v.u >> 16) & 1u);
    return (unsigned short)(r >> 16);
}
__device__ __forceinline__ float bf2f(unsigned short h) {
    union { unsigned u; float f; } v; v.u = ((unsigned)h) << 16;
    return v.f;
}
__device__ __forceinline__ f32x4 mfma16(s16x8 a, s16x8 b, f32x4 c) {
    return __builtin_amdgcn_mfma_f32_16x16x32_f16(
        __builtin_bit_cast(f16x8, a), __builtin_bit_cast(f16x8, b), c, 0, 0, 0);
}

// ---------------- K1 (fallback only): transpose weights to [p][k][j] ----------------
__global__ void k_prep_w(const float* __restrict__ x2h, const float* __restrict__ h2h,
                         float* __restrict__ wxT, float* __restrict__ whT) {
    int idx = blockIdx.x * 256 + threadIdx.x;
    if (idx >= NP * DIM * G3) return;
    int j = idx % G3;
    int k = (idx / G3) % DIM;
    int p = idx / (G3 * DIM);
    wxT[idx] = x2h[((size_t)p * G3 + j) * DIM + k];
    whT[idx] = h2h[((size_t)p * G3 + j) * DIM + k];
}

// ---------------- K1b: Wx AND Wh -> fp16 A-fragments (single term) ----------------
// frag f = ((p*24 + mt)*4 + ks)*64 + lane ; holds W[p][mt*16 + (lane&15)]
// [ks*32 + (lane>>4)*8 + 0..7]. lo slot = fp16 residual*2^11 (unread; kept
// for layout symmetry).
__global__ __launch_bounds__(256) void k_prep_wA(const float* __restrict__ x2h,
                                                 const float* __restrict__ h2h,
                                                 short* __restrict__ wxA_hi,
                                                 short* __restrict__ wxA_lo,
                                                 short* __restrict__ whA_hi,
                                                 short* __restrict__ whA_lo) {
    int e = blockIdx.x * 256 + threadIdx.x;       // 2*18432 = 36864
    if (e >= 2 * NP * 24 * 4 * 64) return;
    int which = (e >= NP * 24 * 4 * 64);
    int f = which ? e - NP * 24 * 4 * 64 : e;
    const float* tab = which ? h2h : x2h;
    short* dh = which ? whA_hi : wxA_hi;
    short* dl = which ? whA_lo : wxA_lo;
    int lane = f & 63;
    int ks = (f >> 6) & 3;
    int mt = (f >> 8) % 24;
    int p  = f / 6144;
    int j = mt * 16 + (lane & 15);
    int d = ks * 32 + (lane >> 4) * 8;
    const float* src = tab + ((size_t)p * G3 + j) * DIM + d;
    short hi[8], lo[8];
#pragma unroll
    for (int u = 0; u < 8; ++u) {
        float x = src[u];
        _Float16 hf = (_Float16)x;                      // RNE
        _Float16 lf = (_Float16)((x - (float)hf) * 2048.f);
        hi[u] = __builtin_bit_cast(short, hf);
        lo[u] = __builtin_bit_cast(short, lf);
    }
    *(s16x8*)(dh + (size_t)f * 8) = *(const s16x8*)hi;
    *(s16x8*)(dl + (size_t)f * 8) = *(const s16x8*)lo;
}

// ---------------- K2: per-item norm + softmax(g) + c = g/norm ----------------
__global__ __launch_bounds__(256) void k_gc(const float* __restrict__ emb,
                                            const float* __restrict__ pt,
                                            float* __restrict__ g, float* __restrict__ c) {
    __shared__ float pt_l[G3];
    __shared__ float ainv[NP];
    int tid = threadIdx.x;
    for (int u = tid; u < G3; u += 256) pt_l[u] = pt[u];
    __syncthreads();
    if (tid < NP) {
        float ss = 0.f;
        for (int k = 0; k < DIM; ++k) { float v = pt_l[tid * DIM + k]; ss += v * v; }
        ainv[tid] = 1.f / fmaxf(sqrtf(ss), 1e-12f);
    }
    __syncthreads();
    int lane = tid & 63, wv = tid >> 6;
    for (int it = 0; it < 8; ++it) {
        int i = blockIdx.x * 32 + wv * 8 + it;
        if (i >= N_ITEMS) continue;
        float a = emb[(size_t)i * DIM + lane];
        float b = emb[(size_t)i * DIM + 64 + lane];
        float ss = a * a + b * b;
        float d0 = a * pt_l[lane]       + b * pt_l[64 + lane];
        float d1 = a * pt_l[128 + lane] + b * pt_l[192 + lane];
        float d2 = a * pt_l[256 + lane] + b * pt_l[320 + lane];
        for (int off = 32; off > 0; off >>= 1) {
            ss += __shfl_down(ss, off);
            d0 += __shfl_down(d0, off);
            d1 += __shfl_down(d1, off);
            d2 += __shfl_down(d2, off);
        }
        if (lane == 0) {
            if (i == 0) {
                g[0] = 0.f; g[1] = 0.f; g[2] = 0.f;
                c[0] = 0.f; c[1] = 0.f; c[2] = 0.f;
            } else {
                float inv = 1.f / fmaxf(sqrtf(ss), 1e-12f);
                float l0 = d0 * ainv[0] * inv * (1.f / TAU);
                float l1 = d1 * ainv[1] * inv * (1.f / TAU);
                float l2 = d2 * ainv[2] * inv * (1.f / TAU);
                float m = fmaxf(l0, fmaxf(l1, l2));
                float e0 = expf(l0 - m), e1 = expf(l1 - m), e2 = expf(l2 - m);
                float is = 1.f / (e0 + e1 + e2);
                float g0 = e0 * is, g1 = e1 * is, g2 = e2 * is;
                g[(size_t)i * 3 + 0] = g0; g[(size_t)i * 3 + 1] = g1; g[(size_t)i * 3 + 2] = g2;
                c[(size_t)i * 3 + 0] = g0 * inv; c[(size_t)i * 3 + 1] = g1 * inv; c[(size_t)i * 3 + 2] = g2 * inv;
            }
        }
    }
}

// ---------------- K3 v3: Gx via fp16 single-term MFMA ----------------
// fp16-single recipe validated on k_rnn3 (R5) and k_logits (R7): MFMA
// 108 -> 36 per block, staging conversions ~8 ops -> 2 cvt_pkrtz, LDS /2.
__global__ __launch_bounds__(512, 2) void k_gx_mfma(const int* __restrict__ seq,
                                                    const float* __restrict__ emb,
                                                    const short* __restrict__ wxA,
                                                    float* __restrict__ gx) {
    int bid = blockIdx.x;
    int t  = bid >> 4;
    int b0 = (bid & 15) * 16;
    int tid = threadIdx.x;
    int lane = tid & 63;
    int w = tid >> 6;
    int n = lane & 15;
    int q = lane >> 4;

    __shared__ int idx_l[16];
    __shared__ __align__(16) unsigned short xF[2048];   // fp16 [ks*512 + lane*8 + j]

    if (tid < 16) idx_l[tid] = seq[t * NB + b0 + tid];
    __syncthreads();

    {
        int tk = tid >> 5, s = tid & 31;
        float4 v = *(const float4*)(emb + (size_t)idx_l[tk] * DIM + s * 4);
        int k = s * 4;
        int ks = k >> 5, km = k & 31;
        int ln = (km >> 3) * 16 + tk;
        int j0 = km & 7;                  // 0 or 4
        int o = ks * 512 + ln * 8 + j0;
        hf16x2 a01 = __builtin_amdgcn_cvt_pkrtz(v.x, v.y);
        hf16x2 a23 = __builtin_amdgcn_cvt_pkrtz(v.z, v.w);
        *(uint2*)(xF + o) = make_uint2(__builtin_bit_cast(unsigned, a01),
                                       __builtin_bit_cast(unsigned, a23));
    }
    __syncthreads();

    s16x8 bf[4];
#pragma unroll
    for (int ks = 0; ks < 4; ++ks)
        bf[ks] = ((const s16x8*)xF)[ks * 64 + lane];

    float* gxt = gx + (size_t)(t * 3) * NB * G3;
#pragma unroll 3
    for (int ji = 0; ji < 9; ++ji) {
        int pid = w + ji * 8;           // 0..71
        int p = pid / 24, mt = pid % 24;
        f32x4 acc = {0.f, 0.f, 0.f, 0.f};
#pragma unroll
        for (int ks = 0; ks < 4; ++ks) {
            size_t ao = ((((size_t)p * 24 + mt) * 4 + ks) * 64 + lane) * 8;
            s16x8 af = *(const s16x8*)(wxA + ao);
            acc = mfma16(af, bf[ks], acc);
        }
        float* o = gxt + ((size_t)p * NB + b0 + n) * G3 + mt * 16 + q * 4;
        *(float4*)o = make_float4(acc[0], acc[1], acc[2], acc[3]);
    }
}

// ---------------- K4 v7: fp16 2-term recurrence, dual-tile 1024-thread block ----------------
// R7 post-mortem: per SIMD (2 lockstep waves) the matrix pipe (~930cy) and
// VALU/TRANS (~1070cy) run back-to-back with ~0 overlap (5.9 MfmaUtil + 9.0
// VALU device = 31% + 48% active, sum == step). 2 waves can't anti-phase —
// barrier-locked, same sections. v7: 1024 threads = 2 independent 16-col
// batch tiles (waves 0-7 / 8-15) -> 4 waves/SIMD; when one tile's waves sit
// in TRANS chains the other tile's waves feed the matrix pipe.
// Viable now (vs R3's spill disaster) because fp16 v6 is VGPR=64 < the 128
// cap at 4 waves/SIMD. Watch: WRITE_SIZE must stay ~384KB (no scratch).
__global__ __launch_bounds__(1024, 4) void k_rnn3(const int* __restrict__ seq,
                                                  const int* __restrict__ lens,
                                                  const float* __restrict__ g,
                                                  const short* __restrict__ whA_hi,
                                                  const float* __restrict__ gx,
                                                  float* __restrict__ hlast) {
    int bid = blockIdx.x;
    int p  = bid / 8;
    int bg = bid % 8;
    int tid = threadIdx.x;
    int tile2 = tid >> 9;            // 0 or 1 (wave-granular)
    int tl  = tid & 511;
    int lane = tid & 63;
    int w = tl >> 6;                 // 0..7 within tile
    int n = lane & 15;
    int q = lane >> 4;
    int d0 = w * 16 + q * 4;
    int b0 = bg * 32 + tile2 * 16;

    // [cur][tile2][2048]
    __shared__ __align__(16) unsigned short hH[2 * 4096];   // fp16 h-hi
    __shared__ __align__(16) unsigned short hL[2 * 4096];   // fp16 (h-res)*2^11
    __shared__ float conc_s[SEQ * 32];

    for (int u = tid; u < 4096; u += 1024) { hH[u] = 0; hL[u] = 0; }

    for (int e = tid; e < SEQ * 32; e += 1024) {
        int t = e >> 5, b = e & 31;
        int ix = seq[t * NB + bg * 32 + b];
        float cc = g[(size_t)ix * 3 + p];
        conc_s[e] = (cc >= EPS_C) ? cc : 0.f;
    }

    s16x8 whF[3][4];
    int mts0 = w, mts1 = 8 + w, mts2 = 16 + w;
#pragma unroll
    for (int ks = 0; ks < 4; ++ks) {
        size_t o0 = ((((size_t)p * 24 + mts0) * 4 + ks) * 64 + lane) * 8;
        size_t o1 = ((((size_t)p * 24 + mts1) * 4 + ks) * 64 + lane) * 8;
        size_t o2 = ((((size_t)p * 24 + mts2) * 4 + ks) * 64 + lane) * 8;
        whF[0][ks] = *(const s16x8*)(whA_hi + o0);
        whF[1][ks] = *(const s16x8*)(whA_hi + o1);
        whF[2][ks] = *(const s16x8*)(whA_hi + o2);
    }

    int len_n = lens[b0 + n];
    float h0 = 0.f, h1 = 0.f, h2 = 0.f, h3 = 0.f;

    int wks = d0 >> 5;
    int km  = d0 & 31;
    int rl  = (km >> 3) * 16 + n;
    int jj0 = km & 7;
    int widx = wks * 512 + rl * 8 + jj0;      // within-tile (2048-short) offset

    const float* gxbase = gx + ((size_t)p * NB + (b0 + n)) * G3 + d0;
    const size_t tstride = (size_t)3 * NB * G3;

    f32x4 pgr = *(const f32x4*)(gxbase);
    f32x4 pgi = *(const f32x4*)(gxbase + DIM);
    f32x4 pgn = *(const f32x4*)(gxbase + 2 * DIM);

    __syncthreads();

    const float SC = 4.8828125e-4f;   // 2^-11

    int cur = 0;
    for (int t = 0; t < SEQ; ++t) {
        f32x4 grv = pgr, giv = pgi, gnv = pgn;
        int tn = (t + 1 < SEQ) ? (t + 1) : t;
        const float* gp = gxbase + (size_t)tn * tstride;
        pgr = *(const f32x4*)(gp);
        pgi = *(const f32x4*)(gp + DIM);
        pgn = *(const f32x4*)(gp + 2 * DIM);

        float cc = conc_s[t * 32 + tile2 * 16 + n];

        const s16x8* bhp = (const s16x8*)hH + cur * 512 + tile2 * 256 + lane;
        const s16x8* blp = (const s16x8*)hL + cur * 512 + tile2 * 256 + lane;
        s16x8 bh0 = bhp[0],   bh1 = bhp[64],  bh2 = bhp[128], bh3 = bhp[192];
        s16x8 bl0 = blp[0],   bl1 = blp[64],  bl2 = blp[128], bl3 = blp[192];

        // ---- section 1: gate r MFMAs (C-init with gx_r) ----
        f32x4 aA0 = grv, aB0 = {0.f,0.f,0.f,0.f};
        aA0 = mfma16(whF[0][0], bh0, aA0);  aB0 = mfma16(whF[0][0], bl0, aB0);
        aA0 = mfma16(whF[0][1], bh1, aA0);  aB0 = mfma16(whF[0][1], bl1, aB0);
        aA0 = mfma16(whF[0][2], bh2, aA0);  aB0 = mfma16(whF[0][2], bl2, aB0);
        aA0 = mfma16(whF[0][3], bh3, aA0);  aB0 = mfma16(whF[0][3], bl3, aB0);
        __builtin_amdgcn_sched_barrier(0);
        // ---- section 2: VALU r ----
        float rr0 = sigmoidf_fast(fmaf(aB0[0], SC, aA0[0]));
        float rr1 = sigmoidf_fast(fmaf(aB0[1], SC, aA0[1]));
        float rr2 = sigmoidf_fast(fmaf(aB0[2], SC, aA0[2]));
        float rr3 = sigmoidf_fast(fmaf(aB0[3], SC, aA0[3]));
        __builtin_amdgcn_sched_barrier(0);
        // ---- section 3: gate i MFMAs ----
        f32x4 aA1 = giv, aB1 = {0.f,0.f,0.f,0.f};
        aA1 = mfma16(whF[1][0], bh0, aA1);  aB1 = mfma16(whF[1][0], bl0, aB1);
        aA1 = mfma16(whF[1][1], bh1, aA1);  aB1 = mfma16(whF[1][1], bl1, aB1);
        aA1 = mfma16(whF[1][2], bh2, aA1);  aB1 = mfma16(whF[1][2], bl2, aB1);
        aA1 = mfma16(whF[1][3], bh3, aA1);  aB1 = mfma16(whF[1][3], bl3, aB1);
        __builtin_amdgcn_sched_barrier(0);
        // ---- section 4: VALU i ----
        float m20 = cc * sigmoidf_fast(fmaf(aB1[0], SC, aA1[0]));
        float m21 = cc * sigmoidf_fast(fmaf(aB1[1], SC, aA1[1]));
        float m22 = cc * sigmoidf_fast(fmaf(aB1[2], SC, aA1[2]));
        float m23 = cc * sigmoidf_fast(fmaf(aB1[3], SC, aA1[3]));
        __builtin_amdgcn_sched_barrier(0);
        // ---- section 5: gate n MFMAs ----
        f32x4 aA2 = {0.f,0.f,0.f,0.f}, aB2 = {0.f,0.f,0.f,0.f};
        aA2 = mfma16(whF[2][0], bh0, aA2);  aB2 = mfma16(whF[2][0], bl0, aB2);
        aA2 = mfma16(whF[2][1], bh1, aA2);  aB2 = mfma16(whF[2][1], bl1, aB2);
        aA2 = mfma16(whF[2][2], bh2, aA2);  aB2 = mfma16(whF[2][2], bl2, aB2);
        aA2 = mfma16(whF[2][3], bh3, aA2);  aB2 = mfma16(whF[2][3], bl3, aB2);
        __builtin_amdgcn_sched_barrier(0);
        // ---- section 6: VALU n + h update + pack + LDS write ----
        float hn0 = fmaf(aB2[0], SC, aA2[0]);
        float hn1 = fmaf(aB2[1], SC, aA2[1]);
        float hn2 = fmaf(aB2[2], SC, aA2[2]);
        float hn3 = fmaf(aB2[3], SC, aA2[3]);
        float ng0 = tanhf_fast(fmaf(rr0, hn0, gnv[0]));
        float ng1 = tanhf_fast(fmaf(rr1, hn1, gnv[1]));
        float ng2 = tanhf_fast(fmaf(rr2, hn2, gnv[2]));
        float ng3 = tanhf_fast(fmaf(rr3, hn3, gnv[3]));
        float hnew0 = fmaf(m20, ng0 - h0, h0);
        float hnew1 = fmaf(m21, ng1 - h1, h1);
        float hnew2 = fmaf(m22, ng2 - h2, h2);
        float hnew3 = fmaf(m23, ng3 - h3, h3);
        h0 = hnew0; h1 = hnew1; h2 = hnew2; h3 = hnew3;

        if (t == len_n - 1) {
            float* hp = hlast + (size_t)(b0 + n) * G3 + p * DIM + d0;
            *(float4*)hp = make_float4(h0, h1, h2, h3);
        }

        // fp16 hi + scaled-residual split via v_cvt_pkrtz (residual exact in f32)
        hf16x2 c01 = __builtin_amdgcn_cvt_pkrtz(hnew0, hnew1);
        hf16x2 c23 = __builtin_amdgcn_cvt_pkrtz(hnew2, hnew3);
        float e0 = (hnew0 - (float)c01[0]) * 2048.f;
        float e1 = (hnew1 - (float)c01[1]) * 2048.f;
        float e2 = (hnew2 - (float)c23[0]) * 2048.f;
        float e3 = (hnew3 - (float)c23[1]) * 2048.f;
        hf16x2 d01 = __builtin_amdgcn_cvt_pkrtz(e0, e1);
        hf16x2 d23 = __builtin_amdgcn_cvt_pkrtz(e2, e3);
        int wb = (cur ^ 1) * 4096 + tile2 * 2048 + widx;
        *(uint2*)(hH + wb) = make_uint2(__builtin_bit_cast(unsigned, c01),
                                        __builtin_bit_cast(unsigned, c23));
        *(uint2*)(hL + wb) = make_uint2(__builtin_bit_cast(unsigned, d01),
                                        __builtin_bit_cast(unsigned, d23));

        // Barrier WITHOUT vmcnt drain: only LDS needs cross-wave ordering;
        // the gx prefetch stays in flight across the barrier.
        asm volatile("s_waitcnt lgkmcnt(0)" ::: "memory");
        __builtin_amdgcn_sched_barrier(0);
        __builtin_amdgcn_s_barrier();
        __builtin_amdgcn_sched_barrier(0);
        cur ^= 1;
    }
}

// ---------------- K4 fallback (no gx buffer) ----------------
__global__ __launch_bounds__(384) void k_rnn(const int* __restrict__ seq,
                                             const int* __restrict__ lens,
                                             const float* __restrict__ emb,
                                             const float* __restrict__ g,
                                             const float* __restrict__ wxT,
                                             const float* __restrict__ whT,
                                             float* __restrict__ hlast) {
    int bid = blockIdx.x;
    int b0 = (bid & 63) * 4;
    int p = bid >> 6;
    __shared__ __align__(16) float h_l[DIM * 4];
    __shared__ __align__(16) float x_l[DIM * 4];
    __shared__ __align__(16) float sx_l[G3 * 4];
    __shared__ __align__(16) float sh_l[G3 * 4];
    __shared__ float conc_l[4];
    __shared__ int idx_l[4];
    __shared__ int len_l[4];
    int tid = threadIdx.x;
    if (tid < 4) len_l[tid] = lens[b0 + tid];
    for (int u = tid; u < DIM * 4; u += 384) h_l[u] = 0.f;
    __syncthreads();
    const float* wh = whT + (size_t)p * (DIM * G3);
    const float* wx = wxT + (size_t)p * (DIM * G3);
    for (int t = 0; t < SEQ; ++t) {
        if (tid < 4) {
            int ix = seq[t * NB + b0 + tid];
            idx_l[tid] = ix;
            conc_l[tid] = g[(size_t)ix * 3 + p];
        }
        __syncthreads();
        for (int u = tid; u < DIM * 4; u += 384) {
            int bc = u >> 7, k = u & 127;
            x_l[k * 4 + bc] = emb[(size_t)idx_l[bc] * DIM + k];
        }
        __syncthreads();
        int j = tid;
        float ax0 = 0.f, ax1 = 0.f, ax2 = 0.f, ax3 = 0.f;
#pragma unroll 4
        for (int k = 0; k < DIM; ++k) {
            float wv = wx[(size_t)k * G3 + j];
            float4 xv = *(const float4*)(x_l + k * 4);
            ax0 += wv * xv.x; ax1 += wv * xv.y; ax2 += wv * xv.z; ax3 += wv * xv.w;
        }
        float ah0 = 0.f, ah1 = 0.f, ah2 = 0.f, ah3 = 0.f;
#pragma unroll 4
        for (int k = 0; k < DIM; ++k) {
            float wv = wh[(size_t)k * G3 + j];
            float4 hv = *(const float4*)(h_l + k * 4);
            ah0 += wv * hv.x; ah1 += wv * hv.y; ah2 += wv * hv.z; ah3 += wv * hv.w;
        }
        *(float4*)(sx_l + j * 4) = make_float4(ax0, ax1, ax2, ax3);
        *(float4*)(sh_l + j * 4) = make_float4(ah0, ah1, ah2, ah3);
        __syncthreads();
        for (int u = tid; u < DIM * 4; u += 384) {
            int bc = u & 3, d = u >> 2;
            float sr = sx_l[d * 4 + bc] + sh_l[d * 4 + bc];
            float si = sx_l[(DIM + d) * 4 + bc] + sh_l[(DIM + d) * 4 + bc];
            float xn = sx_l[(2 * DIM + d) * 4 + bc];
            float hn = sh_l[(2 * DIM + d) * 4 + bc];
            float r  = sigmoidf_fast(sr);
            float ig = sigmoidf_fast(si);
            float ng = tanhf_fast(xn + r * hn);
            float h  = h_l[d * 4 + bc];
            float cc = conc_l[bc];
            float multi = (cc >= EPS_C ? cc : 0.f) * ig;
            float hnew = h + multi * (ng - h);
            h_l[d * 4 + bc] = hnew;
            if (t == len_l[bc] - 1)
                hlast[(size_t)(b0 + bc) * G3 + p * DIM + d] = hnew;
        }
        __syncthreads();
    }
}

// ---------------- K4.5: hlast -> fp16 A-fragments (single term) ----------------
__global__ __launch_bounds__(256) void k_prep_h(const float* __restrict__ hlast,
                                                short* __restrict__ hl_hi) {
    int e = blockIdx.x * 256 + threadIdx.x;       // 98304
    int b = e / G3;
    int k = e % G3;
    float x = hlast[e];
    _Float16 hf = (_Float16)x;                    // RNE, |h|<1 -> exact range
    int off = (k >> 5) * 8192 + b * 32 + ((k >> 3) & 3) * 8 + (k & 7);
    hl_hi[off] = __builtin_bit_cast(short, hf);
}

// ---------------- K5 v2: logits via fp16 single-term MFMA, out = sigmoid ----------------
__global__ __launch_bounds__(256) void k_logits_mfma(const float* __restrict__ emb,
                                                     const float* __restrict__ c,
                                                     const short* __restrict__ hl_hi,
                                                     float* __restrict__ out) {
    int i0 = blockIdx.x * 64;
    int tid = threadIdx.x;
    int w = tid >> 6;
    int lane = tid & 63;
    int n = lane & 15;
    int q = lane >> 4;

    __shared__ __align__(16) float embs[64 * 132];

    for (int u = tid; u < 64 * 32; u += 256) {
        int i = u >> 5;
        int s = u & 31;
        int gi = i0 + i;
        float4 v = make_float4(0.f, 0.f, 0.f, 0.f);
        if (gi < N_ITEMS) v = *(const float4*)(emb + (size_t)gi * DIM + s * 4);
        *(float4*)(embs + i * 132 + s * 4) = v;
    }

    float cv[4][3];
#pragma unroll
    for (int is = 0; is < 4; ++is) {
        int gi = i0 + is * 16 + n;
#pragma unroll
        for (int p = 0; p < 3; ++p)
            cv[is][p] = (gi < N_ITEMS) ? c[(size_t)gi * 3 + p] : 0.f;
    }
    __syncthreads();

    f32x4 acc[4][4];
#pragma unroll
    for (int bs = 0; bs < 4; ++bs)
#pragma unroll
        for (int is = 0; is < 4; ++is)
            acc[bs][is] = (f32x4){0.f, 0.f, 0.f, 0.f};

    for (int ks = 0; ks < 12; ++ks) {
        int p = ks >> 2;
        int d0 = (ks & 3) * 32;
        int abase = ks * 8192 + (w * 64 + n) * 32 + q * 8;
        s16x8 ah[4];
#pragma unroll
        for (int bs = 0; bs < 4; ++bs)
            ah[bs] = *(const s16x8*)(hl_hi + abase + bs * 512);
#pragma unroll
        for (int is = 0; is < 4; ++is) {
            const float* src = embs + (is * 16 + n) * 132 + d0 + q * 8;
            float x[8];
            *(float4*)(x)     = *(const float4*)(src);
            *(float4*)(x + 4) = *(const float4*)(src + 4);
            float sc = cv[is][p];
            union { hf16x2 h[4]; s16x8 s; } bf_;
#pragma unroll
            for (int jp = 0; jp < 4; ++jp)
                bf_.h[jp] = __builtin_amdgcn_cvt_pkrtz(x[2 * jp] * sc, x[2 * jp + 1] * sc);
            s16x8 bv = bf_.s;
#pragma unroll
            for (int bs = 0; bs < 4; ++bs)
                acc[bs][is] = mfma16(ah[bs], bv, acc[bs][is]);
        }
    }

#pragma unroll
    for (int is = 0; is < 4; ++is) {
        int gi = i0 + is * 16 + n;
        if (gi >= N_ITEMS) continue;
#pragma unroll
        for (int bs = 0; bs < 4; ++bs) {
            int brow = w * 64 + bs * 16 + q * 4;
#pragma unroll
            for (int r = 0; r < 4; ++r)
                out[(size_t)(brow + r) * N_ITEMS + gi] = sigmoidf_fast(acc[bs][is][r]);
        }
    }
}

extern "C" void kernel_launch(void* const* d_in, const int* in_sizes, int n_in,
                              void* d_out, int out_size, void* d_ws, size_t ws_size,
                              hipStream_t stream) {
    const int*   seq  = (const int*)d_in[0];
    const int*   lens = (const int*)d_in[1];
    const float* emb  = (const float*)d_in[2];
    const float* pt   = (const float*)d_in[3];
    const float* x2h  = (const float*)d_in[4];
    const float* h2h  = (const float*)d_in[5];
    float* out = (float*)d_out;
    float* ws  = (float*)d_ws;

    float* g     = ws + OFF_G;
    float* c     = ws + OFF_C;
    float* wxT   = ws + OFF_WXT;
    float* whT   = ws + OFF_WHT;
    float* hlast = ws + OFF_HLAST;
    float* gxbuf = ws + OFF_GX;
    short* wxA_hi = (short*)(ws + OFF_WXT);
    short* wxA_lo = wxA_hi + 147456;
    short* whA_hi = (short*)(ws + OFF_WHT);
    short* whA_lo = whA_hi + 147456;
    short* hl_hi = (short*)(ws + OFF_GX);       // aliases gx (dead after k_rnn3)

    int useGx = (ws_size >= (size_t)WS_FLOATS_PATHA * 4) ? 1 : 0;

    k_gc<<<3126, 256, 0, stream>>>(emb, pt, g, c);
    if (useGx) {
        k_prep_wA<<<144, 256, 0, stream>>>(x2h, h2h, wxA_hi, wxA_lo, whA_hi, whA_lo);
        k_gx_mfma<<<1600, 512, 0, stream>>>(seq, emb, wxA_hi, gxbuf);
        k_rnn3<<<24, 1024, 0, stream>>>(seq, lens, g, whA_hi, gxbuf, hlast);
    } else {
        k_prep_w<<<576, 256, 0, stream>>>(x2h, h2h, wxT, whT);
        k_rnn<<<192, 384, 0, stream>>>(seq, lens, emb, g, wxT, whT, hlast);
    }
    k_prep_h<<<384, 256, 0, stream>>>(hlast, hl_hi);
    k_logits_mfma<<<1563, 256, 0, stream>>>(emb, c, hl_hi, out);
}

// Round 9
// 361.790 us; speedup vs baseline: 1.1802x; 1.1802x over previous
//
#include <hip/hip_runtime.h>
#include <hip/hip_bf16.h>
#include <math.h>

#define N_ITEMS 100001
#define DIM 128
#define NP 3
#define SEQ 100
#define NB 256
#define G3 384           // 3*DIM
#define TAU 0.1f
#define EPS_C 0.01f

// ---------------- ws layout (float offsets) ----------------
#define OFF_G     0
#define OFF_C     300016
#define OFF_WXT   600032
#define OFF_WHT   747488
#define OFF_HLAST 894944
#define OFF_GX    993248
#define WS_FLOATS_PATHA (993248 + 29491200)

typedef float f32x4 __attribute__((ext_vector_type(4)));
typedef short s16x8 __attribute__((ext_vector_type(8)));
typedef unsigned int u32x4 __attribute__((ext_vector_type(4)));
typedef _Float16 f16x8 __attribute__((ext_vector_type(8)));
typedef __fp16 hf16x2 __attribute__((ext_vector_type(2)));   // cvt_pkrtz result type

__device__ __forceinline__ float sigmoidf_fast(float x) {
    return __builtin_amdgcn_rcpf(1.f + __builtin_amdgcn_exp2f(-1.4426950408889634f * x));
}
__device__ __forceinline__ float tanhf_fast(float x) {
    return 1.f - 2.f * __builtin_amdgcn_rcpf(1.f + __builtin_amdgcn_exp2f(2.8853900817779268f * x));
}
__device__ __forceinline__ unsigned short f2bf(float x) {
    union { float f; unsigned u; } v; v.f = x;
    unsigned r = v.u + 0x7fffu + ((v.u >> 16) & 1u);
    return (unsigned short)(r >> 16);
}
__device__ __forceinline__ float bf2f(unsigned short h) {
    union { unsigned u; float f; } v; v.u = ((unsigned)h) << 16;
    return v.f;
}
__device__ __forceinline__ f32x4 mfma16(s16x8 a, s16x8 b, f32x4 c) {
    return __builtin_amdgcn_mfma_f32_16x16x32_f16(
        __builtin_bit_cast(f16x8, a), __builtin_bit_cast(f16x8, b), c, 0, 0, 0);
}

// ---------------- K1 (fallback only): transpose weights to [p][k][j] ----------------
__global__ void k_prep_w(const float* __restrict__ x2h, const float* __restrict__ h2h,
                         float* __restrict__ wxT, float* __restrict__ whT) {
    int idx = blockIdx.x * 256 + threadIdx.x;
    if (idx >= NP * DIM * G3) return;
    int j = idx % G3;
    int k = (idx / G3) % DIM;
    int p = idx / (G3 * DIM);
    wxT[idx] = x2h[((size_t)p * G3 + j) * DIM + k];
    whT[idx] = h2h[((size_t)p * G3 + j) * DIM + k];
}

// ---------------- K1b: Wx AND Wh -> fp16 A-fragments (single term) ----------------
// frag f = ((p*24 + mt)*4 + ks)*64 + lane ; holds W[p][mt*16 + (lane&15)]
// [ks*32 + (lane>>4)*8 + 0..7]. lo slot = fp16 residual*2^11 (unread; kept
// for layout symmetry).
__global__ __launch_bounds__(256) void k_prep_wA(const float* __restrict__ x2h,
                                                 const float* __restrict__ h2h,
                                                 short* __restrict__ wxA_hi,
                                                 short* __restrict__ wxA_lo,
                                                 short* __restrict__ whA_hi,
                                                 short* __restrict__ whA_lo) {
    int e = blockIdx.x * 256 + threadIdx.x;       // 2*18432 = 36864
    if (e >= 2 * NP * 24 * 4 * 64) return;
    int which = (e >= NP * 24 * 4 * 64);
    int f = which ? e - NP * 24 * 4 * 64 : e;
    const float* tab = which ? h2h : x2h;
    short* dh = which ? whA_hi : wxA_hi;
    short* dl = which ? whA_lo : wxA_lo;
    int lane = f & 63;
    int ks = (f >> 6) & 3;
    int mt = (f >> 8) % 24;
    int p  = f / 6144;
    int j = mt * 16 + (lane & 15);
    int d = ks * 32 + (lane >> 4) * 8;
    const float* src = tab + ((size_t)p * G3 + j) * DIM + d;
    short hi[8], lo[8];
#pragma unroll
    for (int u = 0; u < 8; ++u) {
        float x = src[u];
        _Float16 hf = (_Float16)x;                      // RNE
        _Float16 lf = (_Float16)((x - (float)hf) * 2048.f);
        hi[u] = __builtin_bit_cast(short, hf);
        lo[u] = __builtin_bit_cast(short, lf);
    }
    *(s16x8*)(dh + (size_t)f * 8) = *(const s16x8*)hi;
    *(s16x8*)(dl + (size_t)f * 8) = *(const s16x8*)lo;
}

// ---------------- K2: per-item norm + softmax(g) + c = g/norm ----------------
__global__ __launch_bounds__(256) void k_gc(const float* __restrict__ emb,
                                            const float* __restrict__ pt,
                                            float* __restrict__ g, float* __restrict__ c) {
    __shared__ float pt_l[G3];
    __shared__ float ainv[NP];
    int tid = threadIdx.x;
    for (int u = tid; u < G3; u += 256) pt_l[u] = pt[u];
    __syncthreads();
    if (tid < NP) {
        float ss = 0.f;
        for (int k = 0; k < DIM; ++k) { float v = pt_l[tid * DIM + k]; ss += v * v; }
        ainv[tid] = 1.f / fmaxf(sqrtf(ss), 1e-12f);
    }
    __syncthreads();
    int lane = tid & 63, wv = tid >> 6;
    for (int it = 0; it < 8; ++it) {
        int i = blockIdx.x * 32 + wv * 8 + it;
        if (i >= N_ITEMS) continue;
        float a = emb[(size_t)i * DIM + lane];
        float b = emb[(size_t)i * DIM + 64 + lane];
        float ss = a * a + b * b;
        float d0 = a * pt_l[lane]       + b * pt_l[64 + lane];
        float d1 = a * pt_l[128 + lane] + b * pt_l[192 + lane];
        float d2 = a * pt_l[256 + lane] + b * pt_l[320 + lane];
        for (int off = 32; off > 0; off >>= 1) {
            ss += __shfl_down(ss, off);
            d0 += __shfl_down(d0, off);
            d1 += __shfl_down(d1, off);
            d2 += __shfl_down(d2, off);
        }
        if (lane == 0) {
            if (i == 0) {
                g[0] = 0.f; g[1] = 0.f; g[2] = 0.f;
                c[0] = 0.f; c[1] = 0.f; c[2] = 0.f;
            } else {
                float inv = 1.f / fmaxf(sqrtf(ss), 1e-12f);
                float l0 = d0 * ainv[0] * inv * (1.f / TAU);
                float l1 = d1 * ainv[1] * inv * (1.f / TAU);
                float l2 = d2 * ainv[2] * inv * (1.f / TAU);
                float m = fmaxf(l0, fmaxf(l1, l2));
                float e0 = expf(l0 - m), e1 = expf(l1 - m), e2 = expf(l2 - m);
                float is = 1.f / (e0 + e1 + e2);
                float g0 = e0 * is, g1 = e1 * is, g2 = e2 * is;
                g[(size_t)i * 3 + 0] = g0; g[(size_t)i * 3 + 1] = g1; g[(size_t)i * 3 + 2] = g2;
                c[(size_t)i * 3 + 0] = g0 * inv; c[(size_t)i * 3 + 1] = g1 * inv; c[(size_t)i * 3 + 2] = g2 * inv;
            }
        }
    }
}

// ---------------- K3 v3: Gx via fp16 single-term MFMA (kept: R8 Δ ≈ -21us) ----------------
__global__ __launch_bounds__(512, 2) void k_gx_mfma(const int* __restrict__ seq,
                                                    const float* __restrict__ emb,
                                                    const short* __restrict__ wxA,
                                                    float* __restrict__ gx) {
    int bid = blockIdx.x;
    int t  = bid >> 4;
    int b0 = (bid & 15) * 16;
    int tid = threadIdx.x;
    int lane = tid & 63;
    int w = tid >> 6;
    int n = lane & 15;
    int q = lane >> 4;

    __shared__ int idx_l[16];
    __shared__ __align__(16) unsigned short xF[2048];   // fp16 [ks*512 + lane*8 + j]

    if (tid < 16) idx_l[tid] = seq[t * NB + b0 + tid];
    __syncthreads();

    {
        int tk = tid >> 5, s = tid & 31;
        float4 v = *(const float4*)(emb + (size_t)idx_l[tk] * DIM + s * 4);
        int k = s * 4;
        int ks = k >> 5, km = k & 31;
        int ln = (km >> 3) * 16 + tk;
        int j0 = km & 7;                  // 0 or 4
        int o = ks * 512 + ln * 8 + j0;
        hf16x2 a01 = __builtin_amdgcn_cvt_pkrtz(v.x, v.y);
        hf16x2 a23 = __builtin_amdgcn_cvt_pkrtz(v.z, v.w);
        *(uint2*)(xF + o) = make_uint2(__builtin_bit_cast(unsigned, a01),
                                       __builtin_bit_cast(unsigned, a23));
    }
    __syncthreads();

    s16x8 bf[4];
#pragma unroll
    for (int ks = 0; ks < 4; ++ks)
        bf[ks] = ((const s16x8*)xF)[ks * 64 + lane];

    float* gxt = gx + (size_t)(t * 3) * NB * G3;
#pragma unroll 3
    for (int ji = 0; ji < 9; ++ji) {
        int pid = w + ji * 8;           // 0..71
        int p = pid / 24, mt = pid % 24;
        f32x4 acc = {0.f, 0.f, 0.f, 0.f};
#pragma unroll
        for (int ks = 0; ks < 4; ++ks) {
            size_t ao = ((((size_t)p * 24 + mt) * 4 + ks) * 64 + lane) * 8;
            s16x8 af = *(const s16x8*)(wxA + ao);
            acc = mfma16(af, bf[ks], acc);
        }
        float* o = gxt + ((size_t)p * NB + b0 + n) * G3 + mt * 16 + q * 4;
        *(float4*)o = make_float4(acc[0], acc[1], acc[2], acc[3]);
    }
}

// ---------------- K4 v8: single-fp16 h recurrence, 512-thread block ----------------
// R8 post-mortem: 1024-thread dual-tile regressed 1.6x WITHOUT spills — the
// per-step block barrier re-syncs all waves, so more waves/SIMD just scales
// every pinned section's pipe time; anti-phasing is structurally impossible.
// Revert to 512 threads and instead SHORTEN the serial step: drop the h-lo
// residual term (register h stays f32; quantization enters only via Wh*h,
// error ~1.4e-4/step, non-compounding — fp16-single recipe is 3-for-3).
// MFMA 24->12/wave/step, ds_read 8->4, residual-pack VALU deleted.
__global__ __launch_bounds__(512, 2) void k_rnn3(const int* __restrict__ seq,
                                                 const int* __restrict__ lens,
                                                 const float* __restrict__ g,
                                                 const short* __restrict__ whA_hi,
                                                 const float* __restrict__ gx,
                                                 float* __restrict__ hlast) {
    int bid = blockIdx.x;
    int p  = bid / 16;
    int b0 = (bid % 16) * 16;
    int tid = threadIdx.x;
    int lane = tid & 63;
    int w = tid >> 6;
    int n = lane & 15;
    int q = lane >> 4;
    int d0 = w * 16 + q * 4;

    __shared__ __align__(16) unsigned short hH[2 * 2048];   // fp16 h (single term)
    __shared__ float conc_s[SEQ * 16];

    for (int u = tid; u < 2048; u += 512) hH[u] = 0;

    for (int e = tid; e < SEQ * 16; e += 512) {
        int t = e >> 4, b = e & 15;
        int ix = seq[t * NB + b0 + b];
        float cc = g[(size_t)ix * 3 + p];
        conc_s[e] = (cc >= EPS_C) ? cc : 0.f;
    }

    s16x8 whF[3][4];
    int mts0 = w, mts1 = 8 + w, mts2 = 16 + w;
#pragma unroll
    for (int ks = 0; ks < 4; ++ks) {
        size_t o0 = ((((size_t)p * 24 + mts0) * 4 + ks) * 64 + lane) * 8;
        size_t o1 = ((((size_t)p * 24 + mts1) * 4 + ks) * 64 + lane) * 8;
        size_t o2 = ((((size_t)p * 24 + mts2) * 4 + ks) * 64 + lane) * 8;
        whF[0][ks] = *(const s16x8*)(whA_hi + o0);
        whF[1][ks] = *(const s16x8*)(whA_hi + o1);
        whF[2][ks] = *(const s16x8*)(whA_hi + o2);
    }

    int len_n = lens[b0 + n];
    float h0 = 0.f, h1 = 0.f, h2 = 0.f, h3 = 0.f;

    int wks = d0 >> 5;
    int km  = d0 & 31;
    int rl  = (km >> 3) * 16 + n;
    int jj0 = km & 7;
    int widx = wks * 512 + rl * 8 + jj0;

    const float* gxbase = gx + ((size_t)p * NB + (b0 + n)) * G3 + d0;
    const size_t tstride = (size_t)3 * NB * G3;

    f32x4 pgr = *(const f32x4*)(gxbase);
    f32x4 pgi = *(const f32x4*)(gxbase + DIM);
    f32x4 pgn = *(const f32x4*)(gxbase + 2 * DIM);

    __syncthreads();

    int cur = 0;
    for (int t = 0; t < SEQ; ++t) {
        f32x4 grv = pgr, giv = pgi, gnv = pgn;
        int tn = (t + 1 < SEQ) ? (t + 1) : t;
        const float* gp = gxbase + (size_t)tn * tstride;
        pgr = *(const f32x4*)(gp);
        pgi = *(const f32x4*)(gp + DIM);
        pgn = *(const f32x4*)(gp + 2 * DIM);

        float cc = conc_s[t * 16 + n];

        const s16x8* bhp = (const s16x8*)hH + cur * 256 + lane;
        s16x8 bh0 = bhp[0], bh1 = bhp[64], bh2 = bhp[128], bh3 = bhp[192];

        // ---- section 1: gate r MFMAs (C-init with gx_r) ----
        f32x4 aA0 = grv;
        aA0 = mfma16(whF[0][0], bh0, aA0);
        aA0 = mfma16(whF[0][1], bh1, aA0);
        aA0 = mfma16(whF[0][2], bh2, aA0);
        aA0 = mfma16(whF[0][3], bh3, aA0);
        __builtin_amdgcn_sched_barrier(0);
        // ---- section 2: VALU r ----
        float rr0 = sigmoidf_fast(aA0[0]);
        float rr1 = sigmoidf_fast(aA0[1]);
        float rr2 = sigmoidf_fast(aA0[2]);
        float rr3 = sigmoidf_fast(aA0[3]);
        __builtin_amdgcn_sched_barrier(0);
        // ---- section 3: gate i MFMAs ----
        f32x4 aA1 = giv;
        aA1 = mfma16(whF[1][0], bh0, aA1);
        aA1 = mfma16(whF[1][1], bh1, aA1);
        aA1 = mfma16(whF[1][2], bh2, aA1);
        aA1 = mfma16(whF[1][3], bh3, aA1);
        __builtin_amdgcn_sched_barrier(0);
        // ---- section 4: VALU i ----
        float m20 = cc * sigmoidf_fast(aA1[0]);
        float m21 = cc * sigmoidf_fast(aA1[1]);
        float m22 = cc * sigmoidf_fast(aA1[2]);
        float m23 = cc * sigmoidf_fast(aA1[3]);
        __builtin_amdgcn_sched_barrier(0);
        // ---- section 5: gate n MFMAs ----
        f32x4 aA2 = {0.f,0.f,0.f,0.f};
        aA2 = mfma16(whF[2][0], bh0, aA2);
        aA2 = mfma16(whF[2][1], bh1, aA2);
        aA2 = mfma16(whF[2][2], bh2, aA2);
        aA2 = mfma16(whF[2][3], bh3, aA2);
        __builtin_amdgcn_sched_barrier(0);
        // ---- section 6: VALU n + h update + pack + LDS write ----
        float ng0 = tanhf_fast(fmaf(rr0, aA2[0], gnv[0]));
        float ng1 = tanhf_fast(fmaf(rr1, aA2[1], gnv[1]));
        float ng2 = tanhf_fast(fmaf(rr2, aA2[2], gnv[2]));
        float ng3 = tanhf_fast(fmaf(rr3, aA2[3], gnv[3]));
        float hnew0 = fmaf(m20, ng0 - h0, h0);
        float hnew1 = fmaf(m21, ng1 - h1, h1);
        float hnew2 = fmaf(m22, ng2 - h2, h2);
        float hnew3 = fmaf(m23, ng3 - h3, h3);
        h0 = hnew0; h1 = hnew1; h2 = hnew2; h3 = hnew3;

        if (t == len_n - 1) {
            float* hp = hlast + (size_t)(b0 + n) * G3 + p * DIM + d0;
            *(float4*)hp = make_float4(h0, h1, h2, h3);
        }

        hf16x2 c01 = __builtin_amdgcn_cvt_pkrtz(hnew0, hnew1);
        hf16x2 c23 = __builtin_amdgcn_cvt_pkrtz(hnew2, hnew3);
        int wb = (cur ^ 1) * 2048 + widx;
        *(uint2*)(hH + wb) = make_uint2(__builtin_bit_cast(unsigned, c01),
                                        __builtin_bit_cast(unsigned, c23));

        // Barrier WITHOUT vmcnt drain: only LDS needs cross-wave ordering;
        // the gx prefetch stays in flight across the barrier.
        asm volatile("s_waitcnt lgkmcnt(0)" ::: "memory");
        __builtin_amdgcn_sched_barrier(0);
        __builtin_amdgcn_s_barrier();
        __builtin_amdgcn_sched_barrier(0);
        cur ^= 1;
    }
}

// ---------------- K4 fallback (no gx buffer) ----------------
__global__ __launch_bounds__(384) void k_rnn(const int* __restrict__ seq,
                                             const int* __restrict__ lens,
                                             const float* __restrict__ emb,
                                             const float* __restrict__ g,
                                             const float* __restrict__ wxT,
                                             const float* __restrict__ whT,
                                             float* __restrict__ hlast) {
    int bid = blockIdx.x;
    int b0 = (bid & 63) * 4;
    int p = bid >> 6;
    __shared__ __align__(16) float h_l[DIM * 4];
    __shared__ __align__(16) float x_l[DIM * 4];
    __shared__ __align__(16) float sx_l[G3 * 4];
    __shared__ __align__(16) float sh_l[G3 * 4];
    __shared__ float conc_l[4];
    __shared__ int idx_l[4];
    __shared__ int len_l[4];
    int tid = threadIdx.x;
    if (tid < 4) len_l[tid] = lens[b0 + tid];
    for (int u = tid; u < DIM * 4; u += 384) h_l[u] = 0.f;
    __syncthreads();
    const float* wh = whT + (size_t)p * (DIM * G3);
    const float* wx = wxT + (size_t)p * (DIM * G3);
    for (int t = 0; t < SEQ; ++t) {
        if (tid < 4) {
            int ix = seq[t * NB + b0 + tid];
            idx_l[tid] = ix;
            conc_l[tid] = g[(size_t)ix * 3 + p];
        }
        __syncthreads();
        for (int u = tid; u < DIM * 4; u += 384) {
            int bc = u >> 7, k = u & 127;
            x_l[k * 4 + bc] = emb[(size_t)idx_l[bc] * DIM + k];
        }
        __syncthreads();
        int j = tid;
        float ax0 = 0.f, ax1 = 0.f, ax2 = 0.f, ax3 = 0.f;
#pragma unroll 4
        for (int k = 0; k < DIM; ++k) {
            float wv = wx[(size_t)k * G3 + j];
            float4 xv = *(const float4*)(x_l + k * 4);
            ax0 += wv * xv.x; ax1 += wv * xv.y; ax2 += wv * xv.z; ax3 += wv * xv.w;
        }
        float ah0 = 0.f, ah1 = 0.f, ah2 = 0.f, ah3 = 0.f;
#pragma unroll 4
        for (int k = 0; k < DIM; ++k) {
            float wv = wh[(size_t)k * G3 + j];
            float4 hv = *(const float4*)(h_l + k * 4);
            ah0 += wv * hv.x; ah1 += wv * hv.y; ah2 += wv * hv.z; ah3 += wv * hv.w;
        }
        *(float4*)(sx_l + j * 4) = make_float4(ax0, ax1, ax2, ax3);
        *(float4*)(sh_l + j * 4) = make_float4(ah0, ah1, ah2, ah3);
        __syncthreads();
        for (int u = tid; u < DIM * 4; u += 384) {
            int bc = u & 3, d = u >> 2;
            float sr = sx_l[d * 4 + bc] + sh_l[d * 4 + bc];
            float si = sx_l[(DIM + d) * 4 + bc] + sh_l[(DIM + d) * 4 + bc];
            float xn = sx_l[(2 * DIM + d) * 4 + bc];
            float hn = sh_l[(2 * DIM + d) * 4 + bc];
            float r  = sigmoidf_fast(sr);
            float ig = sigmoidf_fast(si);
            float ng = tanhf_fast(xn + r * hn);
            float h  = h_l[d * 4 + bc];
            float cc = conc_l[bc];
            float multi = (cc >= EPS_C ? cc : 0.f) * ig;
            float hnew = h + multi * (ng - h);
            h_l[d * 4 + bc] = hnew;
            if (t == len_l[bc] - 1)
                hlast[(size_t)(b0 + bc) * G3 + p * DIM + d] = hnew;
        }
        __syncthreads();
    }
}

// ---------------- K4.5: hlast -> fp16 A-fragments (single term) ----------------
__global__ __launch_bounds__(256) void k_prep_h(const float* __restrict__ hlast,
                                                short* __restrict__ hl_hi) {
    int e = blockIdx.x * 256 + threadIdx.x;       // 98304
    int b = e / G3;
    int k = e % G3;
    float x = hlast[e];
    _Float16 hf = (_Float16)x;                    // RNE, |h|<1 -> exact range
    int off = (k >> 5) * 8192 + b * 32 + ((k >> 3) & 3) * 8 + (k & 7);
    hl_hi[off] = __builtin_bit_cast(short, hf);
}

// ---------------- K5 v2: logits via fp16 single-term MFMA, out = sigmoid ----------------
__global__ __launch_bounds__(256) void k_logits_mfma(const float* __restrict__ emb,
                                                     const float* __restrict__ c,
                                                     const short* __restrict__ hl_hi,
                                                     float* __restrict__ out) {
    int i0 = blockIdx.x * 64;
    int tid = threadIdx.x;
    int w = tid >> 6;
    int lane = tid & 63;
    int n = lane & 15;
    int q = lane >> 4;

    __shared__ __align__(16) float embs[64 * 132];

    for (int u = tid; u < 64 * 32; u += 256) {
        int i = u >> 5;
        int s = u & 31;
        int gi = i0 + i;
        float4 v = make_float4(0.f, 0.f, 0.f, 0.f);
        if (gi < N_ITEMS) v = *(const float4*)(emb + (size_t)gi * DIM + s * 4);
        *(float4*)(embs + i * 132 + s * 4) = v;
    }

    float cv[4][3];
#pragma unroll
    for (int is = 0; is < 4; ++is) {
        int gi = i0 + is * 16 + n;
#pragma unroll
        for (int p = 0; p < 3; ++p)
            cv[is][p] = (gi < N_ITEMS) ? c[(size_t)gi * 3 + p] : 0.f;
    }
    __syncthreads();

    f32x4 acc[4][4];
#pragma unroll
    for (int bs = 0; bs < 4; ++bs)
#pragma unroll
        for (int is = 0; is < 4; ++is)
            acc[bs][is] = (f32x4){0.f, 0.f, 0.f, 0.f};

    for (int ks = 0; ks < 12; ++ks) {
        int p = ks >> 2;
        int d0 = (ks & 3) * 32;
        int abase = ks * 8192 + (w * 64 + n) * 32 + q * 8;
        s16x8 ah[4];
#pragma unroll
        for (int bs = 0; bs < 4; ++bs)
            ah[bs] = *(const s16x8*)(hl_hi + abase + bs * 512);
#pragma unroll
        for (int is = 0; is < 4; ++is) {
            const float* src = embs + (is * 16 + n) * 132 + d0 + q * 8;
            float x[8];
            *(float4*)(x)     = *(const float4*)(src);
            *(float4*)(x + 4) = *(const float4*)(src + 4);
            float sc = cv[is][p];
            union { hf16x2 h[4]; s16x8 s; } bf_;
#pragma unroll
            for (int jp = 0; jp < 4; ++jp)
                bf_.h[jp] = __builtin_amdgcn_cvt_pkrtz(x[2 * jp] * sc, x[2 * jp + 1] * sc);
            s16x8 bv = bf_.s;
#pragma unroll
            for (int bs = 0; bs < 4; ++bs)
                acc[bs][is] = mfma16(ah[bs], bv, acc[bs][is]);
        }
    }

#pragma unroll
    for (int is = 0; is < 4; ++is) {
        int gi = i0 + is * 16 + n;
        if (gi >= N_ITEMS) continue;
#pragma unroll
        for (int bs = 0; bs < 4; ++bs) {
            int brow = w * 64 + bs * 16 + q * 4;
#pragma unroll
            for (int r = 0; r < 4; ++r)
                out[(size_t)(brow + r) * N_ITEMS + gi] = sigmoidf_fast(acc[bs][is][r]);
        }
    }
}

extern "C" void kernel_launch(void* const* d_in, const int* in_sizes, int n_in,
                              void* d_out, int out_size, void* d_ws, size_t ws_size,
                              hipStream_t stream) {
    const int*   seq  = (const int*)d_in[0];
    const int*   lens = (const int*)d_in[1];
    const float* emb  = (const float*)d_in[2];
    const float* pt   = (const float*)d_in[3];
    const float* x2h  = (const float*)d_in[4];
    const float* h2h  = (const float*)d_in[5];
    float* out = (float*)d_out;
    float* ws  = (float*)d_ws;

    float* g     = ws + OFF_G;
    float* c     = ws + OFF_C;
    float* wxT   = ws + OFF_WXT;
    float* whT   = ws + OFF_WHT;
    float* hlast = ws + OFF_HLAST;
    float* gxbuf = ws + OFF_GX;
    short* wxA_hi = (short*)(ws + OFF_WXT);
    short* wxA_lo = wxA_hi + 147456;
    short* whA_hi = (short*)(ws + OFF_WHT);
    short* whA_lo = whA_hi + 147456;
    short* hl_hi = (short*)(ws + OFF_GX);       // aliases gx (dead after k_rnn3)

    int useGx = (ws_size >= (size_t)WS_FLOATS_PATHA * 4) ? 1 : 0;

    k_gc<<<3126, 256, 0, stream>>>(emb, pt, g, c);
    if (useGx) {
        k_prep_wA<<<144, 256, 0, stream>>>(x2h, h2h, wxA_hi, wxA_lo, whA_hi, whA_lo);
        k_gx_mfma<<<1600, 512, 0, stream>>>(seq, emb, wxA_hi, gxbuf);
        k_rnn3<<<48, 512, 0, stream>>>(seq, lens, g, whA_hi, gxbuf, hlast);
    } else {
        k_prep_w<<<576, 256, 0, stream>>>(x2h, h2h, wxT, whT);
        k_rnn<<<192, 384, 0, stream>>>(seq, lens, emb, g, wxT, whT, hlast);
    }
    k_prep_h<<<384, 256, 0, stream>>>(hlast, hl_hi);
    k_logits_mfma<<<1563, 256, 0, stream>>>(emb, c, hl_hi, out);
}

// Round 10
// 355.153 us; speedup vs baseline: 1.2023x; 1.0187x over previous
//
#include <hip/hip_runtime.h>
#include <hip/hip_bf16.h>
#include <math.h>

#define N_ITEMS 100001
#define DIM 128
#define NP 3
#define SEQ 100
#define NB 256
#define G3 384           // 3*DIM
#define TAU 0.1f
#define EPS_C 0.01f

// ---------------- ws layout (float offsets) ----------------
#define OFF_G     0
#define OFF_C     300016
#define OFF_WXT   600032
#define OFF_WHT   747488
#define OFF_HLAST 894944
#define OFF_GX    993248
#define WS_FLOATS_PATHA (993248 + 29491200)

typedef float f32x4 __attribute__((ext_vector_type(4)));
typedef short s16x8 __attribute__((ext_vector_type(8)));
typedef unsigned int u32x4 __attribute__((ext_vector_type(4)));
typedef _Float16 f16x8 __attribute__((ext_vector_type(8)));
typedef __fp16 hf16x2 __attribute__((ext_vector_type(2)));   // cvt_pkrtz result type

__device__ __forceinline__ float sigmoidf_fast(float x) {
    return __builtin_amdgcn_rcpf(1.f + __builtin_amdgcn_exp2f(-1.4426950408889634f * x));
}
__device__ __forceinline__ float tanhf_fast(float x) {
    return 1.f - 2.f * __builtin_amdgcn_rcpf(1.f + __builtin_amdgcn_exp2f(2.8853900817779268f * x));
}
__device__ __forceinline__ unsigned short f2bf(float x) {
    union { float f; unsigned u; } v; v.f = x;
    unsigned r = v.u + 0x7fffu + ((v.u >> 16) & 1u);
    return (unsigned short)(r >> 16);
}
__device__ __forceinline__ float bf2f(unsigned short h) {
    union { unsigned u; float f; } v; v.u = ((unsigned)h) << 16;
    return v.f;
}
__device__ __forceinline__ f32x4 mfma16(s16x8 a, s16x8 b, f32x4 c) {
    return __builtin_amdgcn_mfma_f32_16x16x32_f16(
        __builtin_bit_cast(f16x8, a), __builtin_bit_cast(f16x8, b), c, 0, 0, 0);
}

// ---------------- K1 (fallback only): transpose weights to [p][k][j] ----------------
__global__ void k_prep_w(const float* __restrict__ x2h, const float* __restrict__ h2h,
                         float* __restrict__ wxT, float* __restrict__ whT) {
    int idx = blockIdx.x * 256 + threadIdx.x;
    if (idx >= NP * DIM * G3) return;
    int j = idx % G3;
    int k = (idx / G3) % DIM;
    int p = idx / (G3 * DIM);
    wxT[idx] = x2h[((size_t)p * G3 + j) * DIM + k];
    whT[idx] = h2h[((size_t)p * G3 + j) * DIM + k];
}

// ---------------- K1b: Wx AND Wh -> fp16 A-fragments (single term) ----------------
__global__ __launch_bounds__(256) void k_prep_wA(const float* __restrict__ x2h,
                                                 const float* __restrict__ h2h,
                                                 short* __restrict__ wxA_hi,
                                                 short* __restrict__ wxA_lo,
                                                 short* __restrict__ whA_hi,
                                                 short* __restrict__ whA_lo) {
    int e = blockIdx.x * 256 + threadIdx.x;       // 2*18432 = 36864
    if (e >= 2 * NP * 24 * 4 * 64) return;
    int which = (e >= NP * 24 * 4 * 64);
    int f = which ? e - NP * 24 * 4 * 64 : e;
    const float* tab = which ? h2h : x2h;
    short* dh = which ? whA_hi : wxA_hi;
    short* dl = which ? whA_lo : wxA_lo;
    int lane = f & 63;
    int ks = (f >> 6) & 3;
    int mt = (f >> 8) % 24;
    int p  = f / 6144;
    int j = mt * 16 + (lane & 15);
    int d = ks * 32 + (lane >> 4) * 8;
    const float* src = tab + ((size_t)p * G3 + j) * DIM + d;
    short hi[8], lo[8];
#pragma unroll
    for (int u = 0; u < 8; ++u) {
        float x = src[u];
        _Float16 hf = (_Float16)x;                      // RNE
        _Float16 lf = (_Float16)((x - (float)hf) * 2048.f);
        hi[u] = __builtin_bit_cast(short, hf);
        lo[u] = __builtin_bit_cast(short, lf);
    }
    *(s16x8*)(dh + (size_t)f * 8) = *(const s16x8*)hi;
    *(s16x8*)(dl + (size_t)f * 8) = *(const s16x8*)lo;
}

// ---------------- K2: per-item norm + softmax(g) + c = g/norm ----------------
__global__ __launch_bounds__(256) void k_gc(const float* __restrict__ emb,
                                            const float* __restrict__ pt,
                                            float* __restrict__ g, float* __restrict__ c) {
    __shared__ float pt_l[G3];
    __shared__ float ainv[NP];
    int tid = threadIdx.x;
    for (int u = tid; u < G3; u += 256) pt_l[u] = pt[u];
    __syncthreads();
    if (tid < NP) {
        float ss = 0.f;
        for (int k = 0; k < DIM; ++k) { float v = pt_l[tid * DIM + k]; ss += v * v; }
        ainv[tid] = 1.f / fmaxf(sqrtf(ss), 1e-12f);
    }
    __syncthreads();
    int lane = tid & 63, wv = tid >> 6;
    for (int it = 0; it < 8; ++it) {
        int i = blockIdx.x * 32 + wv * 8 + it;
        if (i >= N_ITEMS) continue;
        float a = emb[(size_t)i * DIM + lane];
        float b = emb[(size_t)i * DIM + 64 + lane];
        float ss = a * a + b * b;
        float d0 = a * pt_l[lane]       + b * pt_l[64 + lane];
        float d1 = a * pt_l[128 + lane] + b * pt_l[192 + lane];
        float d2 = a * pt_l[256 + lane] + b * pt_l[320 + lane];
        for (int off = 32; off > 0; off >>= 1) {
            ss += __shfl_down(ss, off);
            d0 += __shfl_down(d0, off);
            d1 += __shfl_down(d1, off);
            d2 += __shfl_down(d2, off);
        }
        if (lane == 0) {
            if (i == 0) {
                g[0] = 0.f; g[1] = 0.f; g[2] = 0.f;
                c[0] = 0.f; c[1] = 0.f; c[2] = 0.f;
            } else {
                float inv = 1.f / fmaxf(sqrtf(ss), 1e-12f);
                float l0 = d0 * ainv[0] * inv * (1.f / TAU);
                float l1 = d1 * ainv[1] * inv * (1.f / TAU);
                float l2 = d2 * ainv[2] * inv * (1.f / TAU);
                float m = fmaxf(l0, fmaxf(l1, l2));
                float e0 = expf(l0 - m), e1 = expf(l1 - m), e2 = expf(l2 - m);
                float is = 1.f / (e0 + e1 + e2);
                float g0 = e0 * is, g1 = e1 * is, g2 = e2 * is;
                g[(size_t)i * 3 + 0] = g0; g[(size_t)i * 3 + 1] = g1; g[(size_t)i * 3 + 2] = g2;
                c[(size_t)i * 3 + 0] = g0 * inv; c[(size_t)i * 3 + 1] = g1 * inv; c[(size_t)i * 3 + 2] = g2 * inv;
            }
        }
    }
}

// ---------------- K3 v3: Gx via fp16 single-term MFMA ----------------
__global__ __launch_bounds__(512, 2) void k_gx_mfma(const int* __restrict__ seq,
                                                    const float* __restrict__ emb,
                                                    const short* __restrict__ wxA,
                                                    float* __restrict__ gx) {
    int bid = blockIdx.x;
    int t  = bid >> 4;
    int b0 = (bid & 15) * 16;
    int tid = threadIdx.x;
    int lane = tid & 63;
    int w = tid >> 6;
    int n = lane & 15;
    int q = lane >> 4;

    __shared__ int idx_l[16];
    __shared__ __align__(16) unsigned short xF[2048];   // fp16 [ks*512 + lane*8 + j]

    if (tid < 16) idx_l[tid] = seq[t * NB + b0 + tid];
    __syncthreads();

    {
        int tk = tid >> 5, s = tid & 31;
        float4 v = *(const float4*)(emb + (size_t)idx_l[tk] * DIM + s * 4);
        int k = s * 4;
        int ks = k >> 5, km = k & 31;
        int ln = (km >> 3) * 16 + tk;
        int j0 = km & 7;                  // 0 or 4
        int o = ks * 512 + ln * 8 + j0;
        hf16x2 a01 = __builtin_amdgcn_cvt_pkrtz(v.x, v.y);
        hf16x2 a23 = __builtin_amdgcn_cvt_pkrtz(v.z, v.w);
        *(uint2*)(xF + o) = make_uint2(__builtin_bit_cast(unsigned, a01),
                                       __builtin_bit_cast(unsigned, a23));
    }
    __syncthreads();

    s16x8 bf[4];
#pragma unroll
    for (int ks = 0; ks < 4; ++ks)
        bf[ks] = ((const s16x8*)xF)[ks * 64 + lane];

    float* gxt = gx + (size_t)(t * 3) * NB * G3;
#pragma unroll 3
    for (int ji = 0; ji < 9; ++ji) {
        int pid = w + ji * 8;           // 0..71
        int p = pid / 24, mt = pid % 24;
        f32x4 acc = {0.f, 0.f, 0.f, 0.f};
#pragma unroll
        for (int ks = 0; ks < 4; ++ks) {
            size_t ao = ((((size_t)p * 24 + mt) * 4 + ks) * 64 + lane) * 8;
            s16x8 af = *(const s16x8*)(wxA + ao);
            acc = mfma16(af, bf[ks], acc);
        }
        float* o = gxt + ((size_t)p * NB + b0 + n) * G3 + mt * 16 + q * 4;
        *(float4*)o = make_float4(acc[0], acc[1], acc[2], acc[3]);
    }
}

// ---------------- K4 v8: single-fp16 h recurrence, 512-thread block ----------------
__global__ __launch_bounds__(512, 2) void k_rnn3(const int* __restrict__ seq,
                                                 const int* __restrict__ lens,
                                                 const float* __restrict__ g,
                                                 const short* __restrict__ whA_hi,
                                                 const float* __restrict__ gx,
                                                 float* __restrict__ hlast) {
    int bid = blockIdx.x;
    int p  = bid / 16;
    int b0 = (bid % 16) * 16;
    int tid = threadIdx.x;
    int lane = tid & 63;
    int w = tid >> 6;
    int n = lane & 15;
    int q = lane >> 4;
    int d0 = w * 16 + q * 4;

    __shared__ __align__(16) unsigned short hH[2 * 2048];   // fp16 h (single term)
    __shared__ float conc_s[SEQ * 16];

    for (int u = tid; u < 2048; u += 512) hH[u] = 0;

    for (int e = tid; e < SEQ * 16; e += 512) {
        int t = e >> 4, b = e & 15;
        int ix = seq[t * NB + b0 + b];
        float cc = g[(size_t)ix * 3 + p];
        conc_s[e] = (cc >= EPS_C) ? cc : 0.f;
    }

    s16x8 whF[3][4];
    int mts0 = w, mts1 = 8 + w, mts2 = 16 + w;
#pragma unroll
    for (int ks = 0; ks < 4; ++ks) {
        size_t o0 = ((((size_t)p * 24 + mts0) * 4 + ks) * 64 + lane) * 8;
        size_t o1 = ((((size_t)p * 24 + mts1) * 4 + ks) * 64 + lane) * 8;
        size_t o2 = ((((size_t)p * 24 + mts2) * 4 + ks) * 64 + lane) * 8;
        whF[0][ks] = *(const s16x8*)(whA_hi + o0);
        whF[1][ks] = *(const s16x8*)(whA_hi + o1);
        whF[2][ks] = *(const s16x8*)(whA_hi + o2);
    }

    int len_n = lens[b0 + n];
    float h0 = 0.f, h1 = 0.f, h2 = 0.f, h3 = 0.f;

    int wks = d0 >> 5;
    int km  = d0 & 31;
    int rl  = (km >> 3) * 16 + n;
    int jj0 = km & 7;
    int widx = wks * 512 + rl * 8 + jj0;

    const float* gxbase = gx + ((size_t)p * NB + (b0 + n)) * G3 + d0;
    const size_t tstride = (size_t)3 * NB * G3;

    f32x4 pgr = *(const f32x4*)(gxbase);
    f32x4 pgi = *(const f32x4*)(gxbase + DIM);
    f32x4 pgn = *(const f32x4*)(gxbase + 2 * DIM);

    __syncthreads();

    int cur = 0;
    for (int t = 0; t < SEQ; ++t) {
        f32x4 grv = pgr, giv = pgi, gnv = pgn;
        int tn = (t + 1 < SEQ) ? (t + 1) : t;
        const float* gp = gxbase + (size_t)tn * tstride;
        pgr = *(const f32x4*)(gp);
        pgi = *(const f32x4*)(gp + DIM);
        pgn = *(const f32x4*)(gp + 2 * DIM);

        float cc = conc_s[t * 16 + n];

        const s16x8* bhp = (const s16x8*)hH + cur * 256 + lane;
        s16x8 bh0 = bhp[0], bh1 = bhp[64], bh2 = bhp[128], bh3 = bhp[192];

        // ---- section 1: gate r MFMAs (C-init with gx_r) ----
        f32x4 aA0 = grv;
        aA0 = mfma16(whF[0][0], bh0, aA0);
        aA0 = mfma16(whF[0][1], bh1, aA0);
        aA0 = mfma16(whF[0][2], bh2, aA0);
        aA0 = mfma16(whF[0][3], bh3, aA0);
        __builtin_amdgcn_sched_barrier(0);
        // ---- section 2: VALU r ----
        float rr0 = sigmoidf_fast(aA0[0]);
        float rr1 = sigmoidf_fast(aA0[1]);
        float rr2 = sigmoidf_fast(aA0[2]);
        float rr3 = sigmoidf_fast(aA0[3]);
        __builtin_amdgcn_sched_barrier(0);
        // ---- section 3: gate i MFMAs ----
        f32x4 aA1 = giv;
        aA1 = mfma16(whF[1][0], bh0, aA1);
        aA1 = mfma16(whF[1][1], bh1, aA1);
        aA1 = mfma16(whF[1][2], bh2, aA1);
        aA1 = mfma16(whF[1][3], bh3, aA1);
        __builtin_amdgcn_sched_barrier(0);
        // ---- section 4: VALU i ----
        float m20 = cc * sigmoidf_fast(aA1[0]);
        float m21 = cc * sigmoidf_fast(aA1[1]);
        float m22 = cc * sigmoidf_fast(aA1[2]);
        float m23 = cc * sigmoidf_fast(aA1[3]);
        __builtin_amdgcn_sched_barrier(0);
        // ---- section 5: gate n MFMAs ----
        f32x4 aA2 = {0.f,0.f,0.f,0.f};
        aA2 = mfma16(whF[2][0], bh0, aA2);
        aA2 = mfma16(whF[2][1], bh1, aA2);
        aA2 = mfma16(whF[2][2], bh2, aA2);
        aA2 = mfma16(whF[2][3], bh3, aA2);
        __builtin_amdgcn_sched_barrier(0);
        // ---- section 6: VALU n + h update + pack + LDS write ----
        float ng0 = tanhf_fast(fmaf(rr0, aA2[0], gnv[0]));
        float ng1 = tanhf_fast(fmaf(rr1, aA2[1], gnv[1]));
        float ng2 = tanhf_fast(fmaf(rr2, aA2[2], gnv[2]));
        float ng3 = tanhf_fast(fmaf(rr3, aA2[3], gnv[3]));
        float hnew0 = fmaf(m20, ng0 - h0, h0);
        float hnew1 = fmaf(m21, ng1 - h1, h1);
        float hnew2 = fmaf(m22, ng2 - h2, h2);
        float hnew3 = fmaf(m23, ng3 - h3, h3);
        h0 = hnew0; h1 = hnew1; h2 = hnew2; h3 = hnew3;

        if (t == len_n - 1) {
            float* hp = hlast + (size_t)(b0 + n) * G3 + p * DIM + d0;
            *(float4*)hp = make_float4(h0, h1, h2, h3);
        }

        hf16x2 c01 = __builtin_amdgcn_cvt_pkrtz(hnew0, hnew1);
        hf16x2 c23 = __builtin_amdgcn_cvt_pkrtz(hnew2, hnew3);
        int wb = (cur ^ 1) * 2048 + widx;
        *(uint2*)(hH + wb) = make_uint2(__builtin_bit_cast(unsigned, c01),
                                        __builtin_bit_cast(unsigned, c23));

        // Barrier WITHOUT vmcnt drain: only LDS needs cross-wave ordering;
        // the gx prefetch stays in flight across the barrier.
        asm volatile("s_waitcnt lgkmcnt(0)" ::: "memory");
        __builtin_amdgcn_sched_barrier(0);
        __builtin_amdgcn_s_barrier();
        __builtin_amdgcn_sched_barrier(0);
        cur ^= 1;
    }
}

// ---------------- K4 fallback (no gx buffer) ----------------
__global__ __launch_bounds__(384) void k_rnn(const int* __restrict__ seq,
                                             const int* __restrict__ lens,
                                             const float* __restrict__ emb,
                                             const float* __restrict__ g,
                                             const float* __restrict__ wxT,
                                             const float* __restrict__ whT,
                                             float* __restrict__ hlast) {
    int bid = blockIdx.x;
    int b0 = (bid & 63) * 4;
    int p = bid >> 6;
    __shared__ __align__(16) float h_l[DIM * 4];
    __shared__ __align__(16) float x_l[DIM * 4];
    __shared__ __align__(16) float sx_l[G3 * 4];
    __shared__ __align__(16) float sh_l[G3 * 4];
    __shared__ float conc_l[4];
    __shared__ int idx_l[4];
    __shared__ int len_l[4];
    int tid = threadIdx.x;
    if (tid < 4) len_l[tid] = lens[b0 + tid];
    for (int u = tid; u < DIM * 4; u += 384) h_l[u] = 0.f;
    __syncthreads();
    const float* wh = whT + (size_t)p * (DIM * G3);
    const float* wx = wxT + (size_t)p * (DIM * G3);
    for (int t = 0; t < SEQ; ++t) {
        if (tid < 4) {
            int ix = seq[t * NB + b0 + tid];
            idx_l[tid] = ix;
            conc_l[tid] = g[(size_t)ix * 3 + p];
        }
        __syncthreads();
        for (int u = tid; u < DIM * 4; u += 384) {
            int bc = u >> 7, k = u & 127;
            x_l[k * 4 + bc] = emb[(size_t)idx_l[bc] * DIM + k];
        }
        __syncthreads();
        int j = tid;
        float ax0 = 0.f, ax1 = 0.f, ax2 = 0.f, ax3 = 0.f;
#pragma unroll 4
        for (int k = 0; k < DIM; ++k) {
            float wv = wx[(size_t)k * G3 + j];
            float4 xv = *(const float4*)(x_l + k * 4);
            ax0 += wv * xv.x; ax1 += wv * xv.y; ax2 += wv * xv.z; ax3 += wv * xv.w;
        }
        float ah0 = 0.f, ah1 = 0.f, ah2 = 0.f, ah3 = 0.f;
#pragma unroll 4
        for (int k = 0; k < DIM; ++k) {
            float wv = wh[(size_t)k * G3 + j];
            float4 hv = *(const float4*)(h_l + k * 4);
            ah0 += wv * hv.x; ah1 += wv * hv.y; ah2 += wv * hv.z; ah3 += wv * hv.w;
        }
        *(float4*)(sx_l + j * 4) = make_float4(ax0, ax1, ax2, ax3);
        *(float4*)(sh_l + j * 4) = make_float4(ah0, ah1, ah2, ah3);
        __syncthreads();
        for (int u = tid; u < DIM * 4; u += 384) {
            int bc = u & 3, d = u >> 2;
            float sr = sx_l[d * 4 + bc] + sh_l[d * 4 + bc];
            float si = sx_l[(DIM + d) * 4 + bc] + sh_l[(DIM + d) * 4 + bc];
            float xn = sx_l[(2 * DIM + d) * 4 + bc];
            float hn = sh_l[(2 * DIM + d) * 4 + bc];
            float r  = sigmoidf_fast(sr);
            float ig = sigmoidf_fast(si);
            float ng = tanhf_fast(xn + r * hn);
            float h  = h_l[d * 4 + bc];
            float cc = conc_l[bc];
            float multi = (cc >= EPS_C ? cc : 0.f) * ig;
            float hnew = h + multi * (ng - h);
            h_l[d * 4 + bc] = hnew;
            if (t == len_l[bc] - 1)
                hlast[(size_t)(b0 + bc) * G3 + p * DIM + d] = hnew;
        }
        __syncthreads();
    }
}

// ---------------- K4.5: hlast -> fp16 A-fragments (single term) ----------------
__global__ __launch_bounds__(256) void k_prep_h(const float* __restrict__ hlast,
                                                short* __restrict__ hl_hi) {
    int e = blockIdx.x * 256 + threadIdx.x;       // 98304
    int b = e / G3;
    int k = e % G3;
    float x = hlast[e];
    _Float16 hf = (_Float16)x;                    // RNE, |h|<1 -> exact range
    int off = (k >> 5) * 8192 + b * 32 + ((k >> 3) & 3) * 8 + (k & 7);
    hl_hi[off] = __builtin_bit_cast(short, hf);
}

// ---------------- K5 v3: logits, pre-scaled fp16 B in LDS ----------------
// R9 post-mortem: 87.5us with MfmaUtil 8.5 / VALU 16.8 / HBM 21.8 / Occ 9 —
// latency-bound: VGPR 136 capped residency at 3 waves/SIMD and the per-(ks,is)
// LDS-read -> 8 mul + 4 cvt -> MFMA chain is serial. v3: the c[item,p] scale
// multiplies a whole B-column, so pre-scale+convert emb to fp16 for all 3 p
// at STAGING (LDS [p][64][136] fp16, 51KB; stride 136 keeps 16B alignment,
// conflict-free quads). Main loop = pure ds_read_b128 + MFMA, zero VALU.
// Same f32-product-then-cvt_pkrtz rounding -> bit-identical output.
__global__ __launch_bounds__(256, 4) void k_logits_mfma(const float* __restrict__ emb,
                                                        const float* __restrict__ c,
                                                        const short* __restrict__ hl_hi,
                                                        float* __restrict__ out) {
    int i0 = blockIdx.x * 64;
    int tid = threadIdx.x;
    int w = tid >> 6;
    int lane = tid & 63;
    int n = lane & 15;
    int q = lane >> 4;

#define ESTR 136
    __shared__ __align__(16) unsigned short emb16[3 * 64 * ESTR];

    for (int u = tid; u < 64 * 32; u += 256) {
        int i = u >> 5;
        int s = u & 31;
        int gi = i0 + i;
        float4 v = make_float4(0.f, 0.f, 0.f, 0.f);
        float c0 = 0.f, c1 = 0.f, c2 = 0.f;
        if (gi < N_ITEMS) {
            v = *(const float4*)(emb + (size_t)gi * DIM + s * 4);
            c0 = c[(size_t)gi * 3 + 0];
            c1 = c[(size_t)gi * 3 + 1];
            c2 = c[(size_t)gi * 3 + 2];
        }
        int o0 = (0 * 64 + i) * ESTR + s * 4;
        int o1 = (1 * 64 + i) * ESTR + s * 4;
        int o2 = (2 * 64 + i) * ESTR + s * 4;
        hf16x2 a, b2;
        a  = __builtin_amdgcn_cvt_pkrtz(v.x * c0, v.y * c0);
        b2 = __builtin_amdgcn_cvt_pkrtz(v.z * c0, v.w * c0);
        *(uint2*)(emb16 + o0) = make_uint2(__builtin_bit_cast(unsigned, a),
                                           __builtin_bit_cast(unsigned, b2));
        a  = __builtin_amdgcn_cvt_pkrtz(v.x * c1, v.y * c1);
        b2 = __builtin_amdgcn_cvt_pkrtz(v.z * c1, v.w * c1);
        *(uint2*)(emb16 + o1) = make_uint2(__builtin_bit_cast(unsigned, a),
                                           __builtin_bit_cast(unsigned, b2));
        a  = __builtin_amdgcn_cvt_pkrtz(v.x * c2, v.y * c2);
        b2 = __builtin_amdgcn_cvt_pkrtz(v.z * c2, v.w * c2);
        *(uint2*)(emb16 + o2) = make_uint2(__builtin_bit_cast(unsigned, a),
                                           __builtin_bit_cast(unsigned, b2));
    }
    __syncthreads();

    f32x4 acc[4][4];
#pragma unroll
    for (int bs = 0; bs < 4; ++bs)
#pragma unroll
        for (int is = 0; is < 4; ++is)
            acc[bs][is] = (f32x4){0.f, 0.f, 0.f, 0.f};

    for (int ks = 0; ks < 12; ++ks) {
        int p = ks >> 2;
        int kk = ks & 3;
        int abase = ks * 8192 + (w * 64 + n) * 32 + q * 8;
        s16x8 ah[4];
#pragma unroll
        for (int bs = 0; bs < 4; ++bs)
            ah[bs] = *(const s16x8*)(hl_hi + abase + bs * 512);
#pragma unroll
        for (int is = 0; is < 4; ++is) {
            s16x8 bv = *(const s16x8*)(emb16 + (p * 64 + is * 16 + n) * ESTR + kk * 32 + q * 8);
#pragma unroll
            for (int bs = 0; bs < 4; ++bs)
                acc[bs][is] = mfma16(ah[bs], bv, acc[bs][is]);
        }
    }

#pragma unroll
    for (int is = 0; is < 4; ++is) {
        int gi = i0 + is * 16 + n;
        if (gi >= N_ITEMS) continue;
#pragma unroll
        for (int bs = 0; bs < 4; ++bs) {
            int brow = w * 64 + bs * 16 + q * 4;
#pragma unroll
            for (int r = 0; r < 4; ++r)
                out[(size_t)(brow + r) * N_ITEMS + gi] = sigmoidf_fast(acc[bs][is][r]);
        }
    }
#undef ESTR
}

extern "C" void kernel_launch(void* const* d_in, const int* in_sizes, int n_in,
                              void* d_out, int out_size, void* d_ws, size_t ws_size,
                              hipStream_t stream) {
    const int*   seq  = (const int*)d_in[0];
    const int*   lens = (const int*)d_in[1];
    const float* emb  = (const float*)d_in[2];
    const float* pt   = (const float*)d_in[3];
    const float* x2h  = (const float*)d_in[4];
    const float* h2h  = (const float*)d_in[5];
    float* out = (float*)d_out;
    float* ws  = (float*)d_ws;

    float* g     = ws + OFF_G;
    float* c     = ws + OFF_C;
    float* wxT   = ws + OFF_WXT;
    float* whT   = ws + OFF_WHT;
    float* hlast = ws + OFF_HLAST;
    float* gxbuf = ws + OFF_GX;
    short* wxA_hi = (short*)(ws + OFF_WXT);
    short* wxA_lo = wxA_hi + 147456;
    short* whA_hi = (short*)(ws + OFF_WHT);
    short* whA_lo = whA_hi + 147456;
    short* hl_hi = (short*)(ws + OFF_GX);       // aliases gx (dead after k_rnn3)

    int useGx = (ws_size >= (size_t)WS_FLOATS_PATHA * 4) ? 1 : 0;

    k_gc<<<3126, 256, 0, stream>>>(emb, pt, g, c);
    if (useGx) {
        k_prep_wA<<<144, 256, 0, stream>>>(x2h, h2h, wxA_hi, wxA_lo, whA_hi, whA_lo);
        k_gx_mfma<<<1600, 512, 0, stream>>>(seq, emb, wxA_hi, gxbuf);
        k_rnn3<<<48, 512, 0, stream>>>(seq, lens, g, whA_hi, gxbuf, hlast);
    } else {
        k_prep_w<<<576, 256, 0, stream>>>(x2h, h2h, wxT, whT);
        k_rnn<<<192, 384, 0, stream>>>(seq, lens, emb, g, wxT, whT, hlast);
    }
    k_prep_h<<<384, 256, 0, stream>>>(hlast, hl_hi);
    k_logits_mfma<<<1563, 256, 0, stream>>>(emb, c, hl_hi, out);
}